// Round 4
// baseline (1668.922 us; speedup 1.0000x reference)
//
#include <hip/hip_runtime.h>

// LSTMTrafficPredictor: fused 2-layer LSTM + FC head, fp32.
// B=2048, T=512, IN=4, H1=64, H2=32, FC=16, OUT=1.
// R3 design: BLK=512, NB=4, grid=512 -> 2 blocks/CU. K-split weights:
//   layer1: thread = (row r=t&255, K-half q=t>>8)      -> 34 floats
//   layer2: thread = (row r2=t&127, K-quarter q2=t>>7) -> 24 floats
// R3 showed the allocator parks pinned weights in AGPRs (VGPR_Count=60 < 58
// weights) and pays one v_accvgpr_read per *use* (~232/step -> VALU 2.7x the
// FMA floor). R4: pin weights into AGPRs deliberately ("+a") and issue ONE
// explicit v_accvgpr_read per weight per step, reusing the VGPR temp across
// the NB=4 batch FMAs. 3 barriers/step; x fully staged in LDS (32 KB).

#define T_LEN 512
#define IN_F  4
#define H1    64
#define H2    32
#define FCN   16
#define NB    4
#define BLK   512

// Pin a value into an AGPR (deterministic residency, tiny arch-VGPR cost).
#define APIN(v) asm volatile("" : "+a"(v))
// Explicit single AGPR->VGPR read; volatile so it is NOT hoisted out of the
// step loop (hoisting all 58 would need 58 live temps -> spill).
#define AREAD(d, s) asm volatile("v_accvgpr_read_b32 %0, %1" : "=v"(d) : "a"(s))

__device__ __forceinline__ float sigm(float x) {
    return 1.0f / (1.0f + __expf(-x));
}
__device__ __forceinline__ float tanh_(float x) {
    // 1 - 2/(e^{2x}+1): saturates correctly for large |x|
    return 1.0f - 2.0f / (__expf(2.0f * x) + 1.0f);
}

__global__ __launch_bounds__(BLK, 4)
void lstm_fused(const float* __restrict__ x,
                const float* __restrict__ Wih1, const float* __restrict__ Whh1,
                const float* __restrict__ bih1, const float* __restrict__ bhh1,
                const float* __restrict__ Wih2, const float* __restrict__ Whh2,
                const float* __restrict__ bih2, const float* __restrict__ bhh2,
                const float* __restrict__ fc1_w, const float* __restrict__ fc1_b,
                const float* __restrict__ fc2_w, const float* __restrict__ fc2_b,
                float* __restrict__ out)
{
    __shared__ __align__(16) float x_s[NB * T_LEN * IN_F];   // 32 KB
    __shared__ __align__(16) float g1p[2 * NB * 4 * H1];     // 8 KB  [q][b][256]
    __shared__ __align__(16) float g2p[4 * NB * 4 * H2];     // 8 KB  [q2][b][128]
    __shared__ __align__(16) float h1_s[NB][H1];             // 1 KB
    __shared__ __align__(16) float h2_s[NB][H2];             // 0.5 KB

    const int t  = threadIdx.x;
    const int b0 = blockIdx.x * NB;

    // ---- roles ----
    const int r    = t & 255;        // layer1 gate row
    const int q    = t >> 8;         // layer1 K-half (0..1)
    const int qo1  = q * 32;         // h1 column offset
    const int r2   = t & 127;        // layer2 gate row
    const int q2   = t >> 7;         // layer2 K-quarter (0..3)
    const int qo2  = q2 * 16;        // h1 column offset (layer2)
    const int qo2h = q2 * 8;         // h2 column offset (layer2)

    // ---- load weights (58 floats/thread), unpack to scalars, pin to AGPRs ----
    float w1f[32], w2af[16], w2hf[8], wxf[2], b1r, b2r;
    {
        const float2 wx = *(const float2*)&Wih1[r * IN_F + q * 2];
        wxf[0] = wx.x; wxf[1] = wx.y;
        #pragma unroll
        for (int j = 0; j < 8; ++j) {
            const float4 v = *(const float4*)&Whh1[r * H1 + qo1 + j * 4];
            w1f[4 * j] = v.x; w1f[4 * j + 1] = v.y; w1f[4 * j + 2] = v.z; w1f[4 * j + 3] = v.w;
        }
        #pragma unroll
        for (int j = 0; j < 4; ++j) {
            const float4 v = *(const float4*)&Wih2[r2 * H1 + qo2 + j * 4];
            w2af[4 * j] = v.x; w2af[4 * j + 1] = v.y; w2af[4 * j + 2] = v.z; w2af[4 * j + 3] = v.w;
        }
        #pragma unroll
        for (int j = 0; j < 2; ++j) {
            const float4 v = *(const float4*)&Whh2[r2 * H2 + qo2h + j * 4];
            w2hf[4 * j] = v.x; w2hf[4 * j + 1] = v.y; w2hf[4 * j + 2] = v.z; w2hf[4 * j + 3] = v.w;
        }
        b1r = (q == 0)  ? (bih1[r] + bhh1[r])   : 0.f;
        b2r = (q2 == 0) ? (bih2[r2] + bhh2[r2]) : 0.f;
    }
    #pragma unroll
    for (int j = 0; j < 32; ++j) APIN(w1f[j]);
    #pragma unroll
    for (int j = 0; j < 16; ++j) APIN(w2af[j]);
    #pragma unroll
    for (int j = 0; j < 8; ++j) APIN(w2hf[j]);
    APIN(wxf[0]); APIN(wxf[1]); APIN(b1r); APIN(b2r);

    // ---- stage ALL of x for our NB batches (coalesced float4) ----
    {
        const float4* src = (const float4*)(x + (size_t)b0 * T_LEN * IN_F);
        float4* dst = (float4*)x_s;
        #pragma unroll
        for (int i = 0; i < (NB * T_LEN * IN_F / 4) / BLK; ++i)
            dst[t + i * BLK] = src[t + i * BLK];
    }

    // ---- init state ----
    float c1 = 0.f;                               // (t<256): b=t>>6, u=t&63
    float c2 = 0.f;                               // (t<128): b=t>>5, u=t&31
    if (t < NB * H1) (&h1_s[0][0])[t] = 0.f;
    if (t < NB * H2) (&h2_s[0][0])[t] = 0.f;
    __syncthreads();

    // ================= main recurrence (3 barriers/step) =================
    #pragma unroll 1
    for (int s = 0; s < T_LEN; ++s) {
        // ---- Phase D(s-1): layer2 state update, folded here (t<128) ----
        if (s > 0 && t < NB * H2) {
            const int b = t >> 5, u = t & (H2 - 1);
            float gi = 0.f, gf = 0.f, gg = 0.f, go = 0.f;
            #pragma unroll
            for (int qq = 0; qq < 4; ++qq) {
                const float* gp = &g2p[qq * (NB * 4 * H2) + b * (4 * H2)];
                gi += gp[u];
                gf += gp[H2 + u];
                gg += gp[2 * H2 + u];
                go += gp[3 * H2 + u];
            }
            gi = sigm(gi); gf = sigm(gf); gg = tanh_(gg); go = sigm(go);
            c2 = fmaf(gf, c2, gi * gg);
            h2_s[b][u] = go * tanh_(c2);
        }

        // ---- Phase A: layer1 partial gates (row r, K-half q, NB batches) ----
        float a[NB];
        {
            float t0, t1, tb;
            AREAD(t0, wxf[0]); AREAD(t1, wxf[1]); AREAD(tb, b1r);
            #pragma unroll
            for (int b = 0; b < NB; ++b) {
                const float2 xv = *(const float2*)&x_s[b * (T_LEN * IN_F) + s * IN_F + q * 2];
                a[b] = fmaf(t1, xv.y, fmaf(t0, xv.x, tb));
            }
        }
        #pragma unroll
        for (int j4 = 0; j4 < 8; ++j4) {
            float u0, u1, u2, u3;
            AREAD(u0, w1f[4 * j4 + 0]);
            AREAD(u1, w1f[4 * j4 + 1]);
            AREAD(u2, w1f[4 * j4 + 2]);
            AREAD(u3, w1f[4 * j4 + 3]);
            #pragma unroll
            for (int b = 0; b < NB; ++b) {
                const float4 hv = *(const float4*)&h1_s[b][qo1 + j4 * 4];
                a[b] = fmaf(u0, hv.x, a[b]);
                a[b] = fmaf(u1, hv.y, a[b]);
                a[b] = fmaf(u2, hv.z, a[b]);
                a[b] = fmaf(u3, hv.w, a[b]);
            }
        }
        #pragma unroll
        for (int b = 0; b < NB; ++b) g1p[q * (NB * 4 * H1) + b * (4 * H1) + r] = a[b];
        __syncthreads();

        // ---- Phase B: layer1 state update (t<256: b=t>>6, u=t&63) ----
        if (t < NB * H1) {
            const int b = t >> 6, u = t & (H1 - 1);
            const float* g0 = &g1p[b * (4 * H1)];
            const float* g1 = &g1p[NB * 4 * H1 + b * (4 * H1)];
            const float gi = sigm(g0[u]           + g1[u]);
            const float gf = sigm(g0[H1 + u]      + g1[H1 + u]);
            const float gg = tanh_(g0[2 * H1 + u] + g1[2 * H1 + u]);
            const float go = sigm(g0[3 * H1 + u]  + g1[3 * H1 + u]);
            c1 = fmaf(gf, c1, gi * gg);
            h1_s[b][u] = go * tanh_(c1);
        }
        __syncthreads();

        // ---- Phase C: layer2 partial gates (row r2, K-quarter q2, NB batches) ----
        float a2[NB];
        {
            float tb;
            AREAD(tb, b2r);
            #pragma unroll
            for (int b = 0; b < NB; ++b) a2[b] = tb;
        }
        #pragma unroll
        for (int j4 = 0; j4 < 4; ++j4) {
            float u0, u1, u2, u3;
            AREAD(u0, w2af[4 * j4 + 0]);
            AREAD(u1, w2af[4 * j4 + 1]);
            AREAD(u2, w2af[4 * j4 + 2]);
            AREAD(u3, w2af[4 * j4 + 3]);
            #pragma unroll
            for (int b = 0; b < NB; ++b) {
                const float4 hv = *(const float4*)&h1_s[b][qo2 + j4 * 4];
                a2[b] = fmaf(u0, hv.x, a2[b]);
                a2[b] = fmaf(u1, hv.y, a2[b]);
                a2[b] = fmaf(u2, hv.z, a2[b]);
                a2[b] = fmaf(u3, hv.w, a2[b]);
            }
        }
        #pragma unroll
        for (int j4 = 0; j4 < 2; ++j4) {
            float u0, u1, u2, u3;
            AREAD(u0, w2hf[4 * j4 + 0]);
            AREAD(u1, w2hf[4 * j4 + 1]);
            AREAD(u2, w2hf[4 * j4 + 2]);
            AREAD(u3, w2hf[4 * j4 + 3]);
            #pragma unroll
            for (int b = 0; b < NB; ++b) {
                const float4 hv = *(const float4*)&h2_s[b][qo2h + j4 * 4];
                a2[b] = fmaf(u0, hv.x, a2[b]);
                a2[b] = fmaf(u1, hv.y, a2[b]);
                a2[b] = fmaf(u2, hv.z, a2[b]);
                a2[b] = fmaf(u3, hv.w, a2[b]);
            }
        }
        #pragma unroll
        for (int b = 0; b < NB; ++b) g2p[q2 * (NB * 4 * H2) + b * (4 * H2) + r2] = a2[b];
        __syncthreads();
    }

    // ---- final layer2 update (step T-1) ----
    if (t < NB * H2) {
        const int b = t >> 5, u = t & (H2 - 1);
        float gi = 0.f, gf = 0.f, gg = 0.f, go = 0.f;
        #pragma unroll
        for (int qq = 0; qq < 4; ++qq) {
            const float* gp = &g2p[qq * (NB * 4 * H2) + b * (4 * H2)];
            gi += gp[u];
            gf += gp[H2 + u];
            gg += gp[2 * H2 + u];
            go += gp[3 * H2 + u];
        }
        gi = sigm(gi); gf = sigm(gf); gg = tanh_(gg); go = sigm(go);
        c2 = fmaf(gf, c2, gi * gg);
        h2_s[b][u] = go * tanh_(c2);
    }
    __syncthreads();

    // ================= FC head on final h2 =================
    float* fc_s = g2p;   // reuse as [NB][FCN]
    if (t < NB * FCN) {
        const int b = t / FCN, j = t % FCN;
        float sacc = fc1_b[j];
        #pragma unroll
        for (int k = 0; k < H2; ++k)
            sacc = fmaf(fc1_w[j * H2 + k], h2_s[b][k], sacc);
        fc_s[b * FCN + j] = fmaxf(sacc, 0.f);
    }
    __syncthreads();
    if (t < NB) {
        float sacc = fc2_b[0];
        #pragma unroll
        for (int j = 0; j < FCN; ++j)
            sacc = fmaf(fc2_w[j], fc_s[t * FCN + j], sacc);
        out[b0 + t] = sacc;
    }
}

extern "C" void kernel_launch(void* const* d_in, const int* in_sizes, int n_in,
                              void* d_out, int out_size, void* d_ws, size_t ws_size,
                              hipStream_t stream) {
    const float* x     = (const float*)d_in[0];
    const float* Wih1  = (const float*)d_in[1];
    const float* Whh1  = (const float*)d_in[2];
    const float* bih1  = (const float*)d_in[3];
    const float* bhh1  = (const float*)d_in[4];
    const float* Wih2  = (const float*)d_in[5];
    const float* Whh2  = (const float*)d_in[6];
    const float* bih2  = (const float*)d_in[7];
    const float* bhh2  = (const float*)d_in[8];
    const float* fc1_w = (const float*)d_in[9];
    const float* fc1_b = (const float*)d_in[10];
    const float* fc2_w = (const float*)d_in[11];
    const float* fc2_b = (const float*)d_in[12];
    float* out = (float*)d_out;

    const int n_batch = 2048;
    dim3 grid(n_batch / NB), block(BLK);
    lstm_fused<<<grid, block, 0, stream>>>(x, Wih1, Whh1, bih1, bhh1,
                                           Wih2, Whh2, bih2, bhh2,
                                           fc1_w, fc1_b, fc2_w, fc2_b, out);
}

// Round 5
// 1191.444 us; speedup vs baseline: 1.4008x; 1.4008x over previous
//
#include <hip/hip_runtime.h>

// LSTMTrafficPredictor: fused 2-layer LSTM + FC head via MFMA (bf16 hi/lo split).
// B=2048, T=512, IN=4, H1=64, H2=32, FC=16, OUT=1.
// R5: the fp32-VALU path plateaued at 1327us with VALUBusy~80%, MfmaUtil=0.
// Move the gate matmuls to the idle matrix pipe. Precision: every fp32 value
// v = hi + lo (bf16 each); gate = Whi@zhi + Whi@zlo + Wlo@zhi -> rel err ~2^-16.
// Block = 16 batches, 256 threads (4 waves), grid = 128.
//   layer1: z1 = [x(4); h1(64); 1@k=68(bias col); 0-pad] K=96, 16 gate-tiles (4/wave)
//   layer2: z2 = [h1(64); h2(32)] K=96, 8 gate-tiles (2/wave)
// Fragment layouts (m89/m91/m120-verified):
//   A-op:  A[m=lane&15][k=(lane>>4)*8+j]  (m = gate row; arg0)
//   B-op:  B[n=lane&15][k=(lane>>4)*8+j]  (n = batch;    arg1)
//   C/D:   row=(lane>>4)*4+reg (gate), col=lane&15 (batch)
// Weight fragments live in registers (MFMA reads VGPR/AGPR natively -> the
// R1-R4 register-residency war is moot). h/gates round-trip LDS.

#define T_LEN 512
#define IN_F  4
#define H1    64
#define H2    32
#define FCN   16
#define MB    16     // batches per block
#define BLK   256
#define ZP    112    // z row pad (bf16 elems), 224 B: 16B-aligned frag reads
#define GP    20     // gates row pad (floats), 80 B: 16B-aligned float4 reads

typedef __attribute__((ext_vector_type(8))) short  s8b;   // 8 bf16 = 4 VGPR
typedef __attribute__((ext_vector_type(4))) float  f4;    // MFMA acc

union S8U { s8b v; unsigned short u[8]; };

__device__ __forceinline__ float sigm(float x)  { return 1.0f / (1.0f + __expf(-x)); }
__device__ __forceinline__ float tanh_(float x) { return 1.0f - 2.0f / (__expf(2.0f * x) + 1.0f); }

__device__ __forceinline__ unsigned short bf16_rne(float f) {
    unsigned u = __float_as_uint(f);
    u = u + 0x7FFFu + ((u >> 16) & 1u);       // round-to-nearest-even
    return (unsigned short)(u >> 16);
}
__device__ __forceinline__ float bf16_f(unsigned short h) {
    return __uint_as_float(((unsigned)h) << 16);
}

__global__ __launch_bounds__(BLK, 1)
void lstm_mfma(const float* __restrict__ x,
               const float* __restrict__ Wih1, const float* __restrict__ Whh1,
               const float* __restrict__ bih1, const float* __restrict__ bhh1,
               const float* __restrict__ Wih2, const float* __restrict__ Whh2,
               const float* __restrict__ bih2, const float* __restrict__ bhh2,
               const float* __restrict__ fc1_w, const float* __restrict__ fc1_b,
               const float* __restrict__ fc2_w, const float* __restrict__ fc2_b,
               float* __restrict__ out)
{
    __shared__ __align__(16) unsigned short zAh[MB][ZP];   // layer1 input, hi
    __shared__ __align__(16) unsigned short zAl[MB][ZP];   // layer1 input, lo
    __shared__ __align__(16) unsigned short zBh[MB][ZP];   // layer2 input, hi
    __shared__ __align__(16) unsigned short zBl[MB][ZP];   // layer2 input, lo
    __shared__ __align__(16) float g1s[256 * GP];          // layer1 gate preacts
    __shared__ __align__(16) float g2s[128 * GP];          // layer2 gate preacts
    __shared__ __align__(16) float h2f[MB * H2];           // final h2 (fp32)

    const int t    = threadIdx.x;
    const int lane = t & 63;
    const int w    = t >> 6;      // wave 0..3
    const int col  = lane & 15;
    const int quad = lane >> 4;
    const int b0   = blockIdx.x * MB;

    // ---- weight fragments into registers (one-time scalar loads) ----
    S8U wf1h[4][3], wf1l[4][3], wf2h[2][3], wf2l[2][3];
    #pragma unroll
    for (int nt = 0; nt < 4; ++nt) {
        const int g = (w * 4 + nt) * 16 + col;            // layer1 gate row
        #pragma unroll
        for (int ks = 0; ks < 3; ++ks) {
            #pragma unroll
            for (int j = 0; j < 8; ++j) {
                const int kk = ks * 32 + quad * 8 + j;
                float wv;
                if      (kk < IN_F)        wv = Wih1[g * IN_F + kk];
                else if (kk < IN_F + H1)   wv = Whh1[g * H1 + (kk - IN_F)];
                else if (kk == IN_F + H1)  wv = bih1[g] + bhh1[g];   // bias col (z=1)
                else                       wv = 0.f;
                const unsigned short hh = bf16_rne(wv);
                wf1h[nt][ks].u[j] = hh;
                wf1l[nt][ks].u[j] = bf16_rne(wv - bf16_f(hh));
            }
        }
    }
    #pragma unroll
    for (int nt = 0; nt < 2; ++nt) {
        const int g = (w * 2 + nt) * 16 + col;            // layer2 gate row
        #pragma unroll
        for (int ks = 0; ks < 3; ++ks) {
            #pragma unroll
            for (int j = 0; j < 8; ++j) {
                const int kk = ks * 32 + quad * 8 + j;
                const float wv = (kk < H1) ? Wih2[g * H1 + kk]
                                           : Whh2[g * H2 + (kk - H1)];
                const unsigned short hh = bf16_rne(wv);
                wf2h[nt][ks].u[j] = hh;
                wf2l[nt][ks].u[j] = bf16_rne(wv - bf16_f(hh));
            }
        }
    }

    // ---- layer2 bias regs (per activation thread: u2 = t&31) ----
    const int u2b = t & 31;
    const float bbI = bih2[u2b]        + bhh2[u2b];
    const float bbF = bih2[32 + u2b]   + bhh2[32 + u2b];
    const float bbG = bih2[64 + u2b]   + bhh2[64 + u2b];
    const float bbO = bih2[96 + u2b]   + bhh2[96 + u2b];

    // ---- init: zero z buffers (h=0 initial state), bias-one column, x[0] ----
    for (int i = t; i < MB * ZP; i += BLK) {
        (&zAh[0][0])[i] = 0; (&zAl[0][0])[i] = 0;
        (&zBh[0][0])[i] = 0; (&zBl[0][0])[i] = 0;
    }
    __syncthreads();
    if (t < MB) zAh[t][IN_F + H1] = 0x3F80;               // z1[b][68] = 1.0 (bias col)
    if (t < 64) {
        const float xv = x[(size_t)(b0 + (t >> 2)) * T_LEN * IN_F + (t & 3)];
        const unsigned short xh = bf16_rne(xv);
        zAh[t >> 2][t & 3] = xh;
        zAl[t >> 2][t & 3] = bf16_rne(xv - bf16_f(xh));
    }
    float c1[4] = {0.f, 0.f, 0.f, 0.f};   // (u=lane, batches w*4..w*4+3)
    float c2[2] = {0.f, 0.f};             // (u2=t&31, batches (t>>5)*2..+1)
    __syncthreads();

    // ================= main recurrence =================
    #pragma unroll 1
    for (int s = 0; s < T_LEN; ++s) {
        // prefetch x for step s+1 (consumed in phase D -> full-step latency hiding)
        float xnext = 0.f;
        if (t < 64 && s < T_LEN - 1)
            xnext = x[(size_t)(b0 + (t >> 2)) * T_LEN * IN_F + (s + 1) * IN_F + (t & 3)];

        // ---- Phase A: layer1 gates via MFMA ----
        s8b za_h[3], za_l[3];
        #pragma unroll
        for (int ks = 0; ks < 3; ++ks) {
            za_h[ks] = *(const s8b*)&zAh[col][ks * 32 + quad * 8];
            za_l[ks] = *(const s8b*)&zAl[col][ks * 32 + quad * 8];
        }
        #pragma unroll
        for (int nt = 0; nt < 4; ++nt) {
            f4 acc = {0.f, 0.f, 0.f, 0.f};
            #pragma unroll
            for (int ks = 0; ks < 3; ++ks) {
                acc = __builtin_amdgcn_mfma_f32_16x16x32_bf16(wf1h[nt][ks].v, za_h[ks], acc, 0, 0, 0);
                acc = __builtin_amdgcn_mfma_f32_16x16x32_bf16(wf1h[nt][ks].v, za_l[ks], acc, 0, 0, 0);
                acc = __builtin_amdgcn_mfma_f32_16x16x32_bf16(wf1l[nt][ks].v, za_h[ks], acc, 0, 0, 0);
            }
            const int g = (w * 4 + nt) * 16 + quad * 4;
            #pragma unroll
            for (int rg = 0; rg < 4; ++rg) g1s[(g + rg) * GP + col] = acc[rg];
        }
        __syncthreads();

        // ---- Phase B: layer1 activations (u=lane, batches w*4..w*4+3) ----
        {
            const int u = lane, bq = w;
            const f4 gi = *(const f4*)&g1s[(u)        * GP + bq * 4];
            const f4 gf = *(const f4*)&g1s[(64 + u)   * GP + bq * 4];
            const f4 gg = *(const f4*)&g1s[(128 + u)  * GP + bq * 4];
            const f4 go = *(const f4*)&g1s[(192 + u)  * GP + bq * 4];
            #pragma unroll
            for (int bi = 0; bi < 4; ++bi) {
                const float I = sigm(gi[bi]), F = sigm(gf[bi]);
                const float G = tanh_(gg[bi]), O = sigm(go[bi]);
                c1[bi] = fmaf(F, c1[bi], I * G);
                const float h = O * tanh_(c1[bi]);
                const unsigned short hh = bf16_rne(h);
                const unsigned short hl = bf16_rne(h - bf16_f(hh));
                const int b = bq * 4 + bi;
                zAh[b][IN_F + u] = hh; zAl[b][IN_F + u] = hl;   // next-step layer1
                zBh[b][u]        = hh; zBl[b][u]        = hl;   // this-step layer2
            }
        }
        __syncthreads();

        // ---- Phase C: layer2 gates via MFMA ----
        s8b zb_h[3], zb_l[3];
        #pragma unroll
        for (int ks = 0; ks < 3; ++ks) {
            zb_h[ks] = *(const s8b*)&zBh[col][ks * 32 + quad * 8];
            zb_l[ks] = *(const s8b*)&zBl[col][ks * 32 + quad * 8];
        }
        #pragma unroll
        for (int nt = 0; nt < 2; ++nt) {
            f4 acc = {0.f, 0.f, 0.f, 0.f};
            #pragma unroll
            for (int ks = 0; ks < 3; ++ks) {
                acc = __builtin_amdgcn_mfma_f32_16x16x32_bf16(wf2h[nt][ks].v, zb_h[ks], acc, 0, 0, 0);
                acc = __builtin_amdgcn_mfma_f32_16x16x32_bf16(wf2h[nt][ks].v, zb_l[ks], acc, 0, 0, 0);
                acc = __builtin_amdgcn_mfma_f32_16x16x32_bf16(wf2l[nt][ks].v, zb_h[ks], acc, 0, 0, 0);
            }
            const int g = (w * 2 + nt) * 16 + quad * 4;
            #pragma unroll
            for (int rg = 0; rg < 4; ++rg) g2s[(g + rg) * GP + col] = acc[rg];
        }
        __syncthreads();

        // ---- Phase D: layer2 activations (u2=t&31, batches (t>>5)*2..+1) ----
        {
            const int u2 = t & 31, bb = (t >> 5) * 2;
            const float2 I2 = *(const float2*)&g2s[(u2)       * GP + bb];
            const float2 F2 = *(const float2*)&g2s[(32 + u2)  * GP + bb];
            const float2 G2 = *(const float2*)&g2s[(64 + u2)  * GP + bb];
            const float2 O2 = *(const float2*)&g2s[(96 + u2)  * GP + bb];
            #pragma unroll
            for (int k = 0; k < 2; ++k) {
                const float I = sigm((k ? I2.y : I2.x) + bbI);
                const float F = sigm((k ? F2.y : F2.x) + bbF);
                const float G = tanh_((k ? G2.y : G2.x) + bbG);
                const float O = sigm((k ? O2.y : O2.x) + bbO);
                c2[k] = fmaf(F, c2[k], I * G);
                const float h = O * tanh_(c2[k]);
                const unsigned short hh = bf16_rne(h);
                const unsigned short hl = bf16_rne(h - bf16_f(hh));
                zBh[bb + k][H1 + u2] = hh;
                zBl[bb + k][H1 + u2] = hl;
                if (s == T_LEN - 1) h2f[(bb + k) * H2 + u2] = h;
            }
        }
        // write x for step s+1 into z1
        if (t < 64 && s < T_LEN - 1) {
            const unsigned short xh = bf16_rne(xnext);
            zAh[t >> 2][t & 3] = xh;
            zAl[t >> 2][t & 3] = bf16_rne(xnext - bf16_f(xh));
        }
        __syncthreads();
    }

    // ================= FC head on final h2 (fp32) =================
    {
        const int b = t >> 4, j = t & 15;
        float s1 = fc1_b[j];
        #pragma unroll
        for (int k = 0; k < H2; ++k)
            s1 = fmaf(fc1_w[j * H2 + k], h2f[b * H2 + k], s1);
        g2s[b * FCN + j] = fmaxf(s1, 0.f);
    }
    __syncthreads();
    if (t < MB) {
        float s2 = fc2_b[0];
        #pragma unroll
        for (int j = 0; j < FCN; ++j)
            s2 = fmaf(fc2_w[j], g2s[t * FCN + j], s2);
        out[b0 + t] = s2;
    }
}

extern "C" void kernel_launch(void* const* d_in, const int* in_sizes, int n_in,
                              void* d_out, int out_size, void* d_ws, size_t ws_size,
                              hipStream_t stream) {
    const float* x     = (const float*)d_in[0];
    const float* Wih1  = (const float*)d_in[1];
    const float* Whh1  = (const float*)d_in[2];
    const float* bih1  = (const float*)d_in[3];
    const float* bhh1  = (const float*)d_in[4];
    const float* Wih2  = (const float*)d_in[5];
    const float* Whh2  = (const float*)d_in[6];
    const float* bih2  = (const float*)d_in[7];
    const float* bhh2  = (const float*)d_in[8];
    const float* fc1_w = (const float*)d_in[9];
    const float* fc1_b = (const float*)d_in[10];
    const float* fc2_w = (const float*)d_in[11];
    const float* fc2_b = (const float*)d_in[12];
    float* out = (float*)d_out;

    const int n_batch = 2048;
    dim3 grid(n_batch / MB), block(BLK);
    lstm_mfma<<<grid, block, 0, stream>>>(x, Wih1, Whh1, bih1, bhh1,
                                          Wih2, Whh2, bih2, bhh2,
                                          fc1_w, fc1_b, fc2_w, fc2_b, out);
}

// Round 6
// 873.396 us; speedup vs baseline: 1.9108x; 1.3642x over previous
//
#include <hip/hip_runtime.h>

// LSTMTrafficPredictor: fused 2-layer LSTM + FC head via MFMA (bf16 hi/lo split).
// B=2048, T=512, IN=4, H1=64, H2=32, FC=16, OUT=1.
// R6: R5 was correct (absmax 6e-5) but starved the chip: grid=128 blocks on
// 256 CUs -> Occupancy 5.9% (= 512 waves / 8192 slots), MfmaUtil 8%, VALU 23%.
// Fix: MB 16->4, grid 512 -> 2 blocks/CU on ALL CUs (barrier overlap, the R3
// lesson). MFMA N-dim 3/4-empty: irrelevant at 8% util. Also: 3 barriers/step
// (phase D folded into B), activation threads remapped to (u=t>>2,b=t&3) for
// 2-way-free LDS banking, z row pad ZP=136 (17*16B) for uniform frag reads.
// Precision: v = hi + lo (bf16 each); gate = Whi@zhi + Whi@zlo + Wlo@zhi.
//   layer1: z1 = [x(4); h1(64); 1(bias col); pad] K=96, 16 gate-tiles (4/wave)
//   layer2: z2 = [h1(64); h2(32)] K=96, 8 gate-tiles (2/wave)
// Fragment layouts (m89/m91/m120-verified):
//   A-op:  A[m=lane&15][k=(lane>>4)*8+j]  (m = gate row; arg0)
//   B-op:  B[n=lane&15][k=(lane>>4)*8+j]  (n = batch;    arg1)
//   C/D:   row=(lane>>4)*4+reg (gate), col=lane&15 (batch)

#define T_LEN 512
#define IN_F  4
#define H1    64
#define H2    32
#define FCN   16
#define MB    4      // batches per block
#define BLK   256
#define ZP    136    // z row pad (bf16): 272 B/row -> 68 dwords (uniform banks)
#define GP    20     // gates row pad (floats)

typedef __attribute__((ext_vector_type(8))) short  s8b;   // 8 bf16 = 4 VGPR
typedef __attribute__((ext_vector_type(4))) float  f4;    // MFMA acc

union S8U { s8b v; unsigned short u[8]; };

__device__ __forceinline__ float sigm(float x)  { return 1.0f / (1.0f + __expf(-x)); }
__device__ __forceinline__ float tanh_(float x) { return 1.0f - 2.0f / (__expf(2.0f * x) + 1.0f); }

__device__ __forceinline__ unsigned short bf16_rne(float f) {
    unsigned u = __float_as_uint(f);
    u = u + 0x7FFFu + ((u >> 16) & 1u);       // round-to-nearest-even
    return (unsigned short)(u >> 16);
}
__device__ __forceinline__ float bf16_f(unsigned short h) {
    return __uint_as_float(((unsigned)h) << 16);
}

__global__ __launch_bounds__(BLK, 2)
void lstm_mfma(const float* __restrict__ x,
               const float* __restrict__ Wih1, const float* __restrict__ Whh1,
               const float* __restrict__ bih1, const float* __restrict__ bhh1,
               const float* __restrict__ Wih2, const float* __restrict__ Whh2,
               const float* __restrict__ bih2, const float* __restrict__ bhh2,
               const float* __restrict__ fc1_w, const float* __restrict__ fc1_b,
               const float* __restrict__ fc2_w, const float* __restrict__ fc2_b,
               float* __restrict__ out)
{
    __shared__ __align__(16) unsigned short zAh[16][ZP];   // layer1 input, hi
    __shared__ __align__(16) unsigned short zAl[16][ZP];   // layer1 input, lo
    __shared__ __align__(16) unsigned short zBh[16][ZP];   // layer2 input, hi
    __shared__ __align__(16) unsigned short zBl[16][ZP];   // layer2 input, lo
    __shared__ __align__(16) float g1s[256 * GP];          // layer1 gate preacts
    __shared__ __align__(16) float g2s[128 * GP];          // layer2 gate preacts
    __shared__ __align__(16) float h2f[MB * H2];           // final h2 (fp32)

    const int t    = threadIdx.x;
    const int lane = t & 63;
    const int w    = t >> 6;      // wave 0..3
    const int col  = lane & 15;
    const int quad = lane >> 4;
    const int b0   = blockIdx.x * MB;

    // activation-thread roles (2-way-free LDS banking)
    const int au = t >> 2;        // layer1 unit 0..63
    const int ab = t & 3;         // batch 0..3
    const int u2 = (t >> 2) & 31; // layer2 unit (threads t<128)

    // ---- weight fragments into registers (one-time scalar loads) ----
    S8U wf1h[4][3], wf1l[4][3], wf2h[2][3], wf2l[2][3];
    #pragma unroll
    for (int nt = 0; nt < 4; ++nt) {
        const int g = (w * 4 + nt) * 16 + col;            // layer1 gate row
        #pragma unroll
        for (int ks = 0; ks < 3; ++ks) {
            #pragma unroll
            for (int j = 0; j < 8; ++j) {
                const int kk = ks * 32 + quad * 8 + j;
                float wv;
                if      (kk < IN_F)        wv = Wih1[g * IN_F + kk];
                else if (kk < IN_F + H1)   wv = Whh1[g * H1 + (kk - IN_F)];
                else if (kk == IN_F + H1)  wv = bih1[g] + bhh1[g];   // bias col (z=1)
                else                       wv = 0.f;
                const unsigned short hh = bf16_rne(wv);
                wf1h[nt][ks].u[j] = hh;
                wf1l[nt][ks].u[j] = bf16_rne(wv - bf16_f(hh));
            }
        }
    }
    #pragma unroll
    for (int nt = 0; nt < 2; ++nt) {
        const int g = (w * 2 + nt) * 16 + col;            // layer2 gate row
        #pragma unroll
        for (int ks = 0; ks < 3; ++ks) {
            #pragma unroll
            for (int j = 0; j < 8; ++j) {
                const int kk = ks * 32 + quad * 8 + j;
                const float wv = (kk < H1) ? Wih2[g * H1 + kk]
                                           : Whh2[g * H2 + (kk - H1)];
                const unsigned short hh = bf16_rne(wv);
                wf2h[nt][ks].u[j] = hh;
                wf2l[nt][ks].u[j] = bf16_rne(wv - bf16_f(hh));
            }
        }
    }

    // ---- layer2 bias regs (per activation thread u2) ----
    const float bbI = bih2[u2]      + bhh2[u2];
    const float bbF = bih2[32 + u2] + bhh2[32 + u2];
    const float bbG = bih2[64 + u2] + bhh2[64 + u2];
    const float bbO = bih2[96 + u2] + bhh2[96 + u2];

    // ---- init: zero z buffers, bias-one column, x[0] ----
    for (int i = t; i < 16 * ZP; i += BLK) {
        (&zAh[0][0])[i] = 0; (&zAl[0][0])[i] = 0;
        (&zBh[0][0])[i] = 0; (&zBl[0][0])[i] = 0;
    }
    __syncthreads();
    if (t < 16) zAh[t][IN_F + H1] = 0x3F80;               // z1[b][68] = 1.0 (bias col)
    if (t < MB * IN_F) {
        const float xv = x[(size_t)(b0 + (t >> 2)) * T_LEN * IN_F + (t & 3)];
        const unsigned short xh = bf16_rne(xv);
        zAh[t >> 2][t & 3] = xh;
        zAl[t >> 2][t & 3] = bf16_rne(xv - bf16_f(xh));
    }
    float c1 = 0.f;   // state for (unit au, batch ab)
    float c2 = 0.f;   // state for (unit u2, batch ab), threads t<128
    __syncthreads();

    // ================= main recurrence (3 barriers/step) =================
    #pragma unroll 1
    for (int s = 0; s < T_LEN; ++s) {
        // prefetch x for step s+1 (written to LDS at end of step)
        float xnext = 0.f;
        if (t < MB * IN_F && s < T_LEN - 1)
            xnext = x[(size_t)(b0 + (t >> 2)) * T_LEN * IN_F + (s + 1) * IN_F + (t & 3)];

        // ---- Phase A: layer1 gates via MFMA ----
        s8b za_h[3], za_l[3];
        #pragma unroll
        for (int ks = 0; ks < 3; ++ks) {
            za_h[ks] = *(const s8b*)&zAh[col][ks * 32 + quad * 8];
            za_l[ks] = *(const s8b*)&zAl[col][ks * 32 + quad * 8];
        }
        #pragma unroll
        for (int nt = 0; nt < 4; ++nt) {
            f4 acc = {0.f, 0.f, 0.f, 0.f};
            #pragma unroll
            for (int ks = 0; ks < 3; ++ks) {
                acc = __builtin_amdgcn_mfma_f32_16x16x32_bf16(wf1h[nt][ks].v, za_h[ks], acc, 0, 0, 0);
                acc = __builtin_amdgcn_mfma_f32_16x16x32_bf16(wf1h[nt][ks].v, za_l[ks], acc, 0, 0, 0);
                acc = __builtin_amdgcn_mfma_f32_16x16x32_bf16(wf1l[nt][ks].v, za_h[ks], acc, 0, 0, 0);
            }
            const int g = (w * 4 + nt) * 16 + quad * 4;
            #pragma unroll
            for (int rg = 0; rg < 4; ++rg) g1s[(g + rg) * GP + col] = acc[rg];
        }
        __syncthreads();

        // ---- Phase B: layer1 activations (unit au, batch ab) ----
        //      + Phase D(s-1): layer2 activations (t<128: unit u2, batch ab)
        if (s > 0 && t < 4 * H2) {
            const float I = sigm(g2s[(u2)      * GP + ab] + bbI);
            const float F = sigm(g2s[(32 + u2) * GP + ab] + bbF);
            const float G = tanh_(g2s[(64 + u2) * GP + ab] + bbG);
            const float O = sigm(g2s[(96 + u2) * GP + ab] + bbO);
            c2 = fmaf(F, c2, I * G);
            const float h = O * tanh_(c2);
            const unsigned short hh = bf16_rne(h);
            zBh[ab][H1 + u2] = hh;
            zBl[ab][H1 + u2] = bf16_rne(h - bf16_f(hh));
        }
        {
            const float I = sigm(g1s[(au)       * GP + ab]);
            const float F = sigm(g1s[(64 + au)  * GP + ab]);
            const float G = tanh_(g1s[(128 + au) * GP + ab]);
            const float O = sigm(g1s[(192 + au) * GP + ab]);
            c1 = fmaf(F, c1, I * G);
            const float h = O * tanh_(c1);
            const unsigned short hh = bf16_rne(h);
            const unsigned short hl = bf16_rne(h - bf16_f(hh));
            zAh[ab][IN_F + au] = hh; zAl[ab][IN_F + au] = hl;   // next-step layer1
            zBh[ab][au]        = hh; zBl[ab][au]        = hl;   // this-step layer2
        }
        __syncthreads();

        // ---- Phase C: layer2 gates via MFMA ----
        s8b zb_h[3], zb_l[3];
        #pragma unroll
        for (int ks = 0; ks < 3; ++ks) {
            zb_h[ks] = *(const s8b*)&zBh[col][ks * 32 + quad * 8];
            zb_l[ks] = *(const s8b*)&zBl[col][ks * 32 + quad * 8];
        }
        #pragma unroll
        for (int nt = 0; nt < 2; ++nt) {
            f4 acc = {0.f, 0.f, 0.f, 0.f};
            #pragma unroll
            for (int ks = 0; ks < 3; ++ks) {
                acc = __builtin_amdgcn_mfma_f32_16x16x32_bf16(wf2h[nt][ks].v, zb_h[ks], acc, 0, 0, 0);
                acc = __builtin_amdgcn_mfma_f32_16x16x32_bf16(wf2h[nt][ks].v, zb_l[ks], acc, 0, 0, 0);
                acc = __builtin_amdgcn_mfma_f32_16x16x32_bf16(wf2l[nt][ks].v, zb_h[ks], acc, 0, 0, 0);
            }
            const int g = (w * 2 + nt) * 16 + quad * 4;
            #pragma unroll
            for (int rg = 0; rg < 4; ++rg) g2s[(g + rg) * GP + col] = acc[rg];
        }
        // write x(s+1) into z1 before the step-closing barrier
        if (t < MB * IN_F && s < T_LEN - 1) {
            const unsigned short xh = bf16_rne(xnext);
            zAh[t >> 2][t & 3] = xh;
            zAl[t >> 2][t & 3] = bf16_rne(xnext - bf16_f(xh));
        }
        __syncthreads();
    }

    // ---- final layer2 update (step T-1) -> h2f ----
    if (t < 4 * H2) {
        const float I = sigm(g2s[(u2)      * GP + ab] + bbI);
        const float F = sigm(g2s[(32 + u2) * GP + ab] + bbF);
        const float G = tanh_(g2s[(64 + u2) * GP + ab] + bbG);
        const float O = sigm(g2s[(96 + u2) * GP + ab] + bbO);
        c2 = fmaf(F, c2, I * G);
        h2f[ab * H2 + u2] = O * tanh_(c2);
    }
    __syncthreads();

    // ================= FC head on final h2 (fp32) =================
    if (t < MB * FCN) {
        const int b = t >> 4, j = t & 15;
        float s1 = fc1_b[j];
        #pragma unroll
        for (int k = 0; k < H2; ++k)
            s1 = fmaf(fc1_w[j * H2 + k], h2f[b * H2 + k], s1);
        g2s[b * FCN + j] = fmaxf(s1, 0.f);
    }
    __syncthreads();
    if (t < MB) {
        float s2 = fc2_b[0];
        #pragma unroll
        for (int j = 0; j < FCN; ++j)
            s2 = fmaf(fc2_w[j], g2s[t * FCN + j], s2);
        out[b0 + t] = s2;
    }
}

extern "C" void kernel_launch(void* const* d_in, const int* in_sizes, int n_in,
                              void* d_out, int out_size, void* d_ws, size_t ws_size,
                              hipStream_t stream) {
    const float* x     = (const float*)d_in[0];
    const float* Wih1  = (const float*)d_in[1];
    const float* Whh1  = (const float*)d_in[2];
    const float* bih1  = (const float*)d_in[3];
    const float* bhh1  = (const float*)d_in[4];
    const float* Wih2  = (const float*)d_in[5];
    const float* Whh2  = (const float*)d_in[6];
    const float* bih2  = (const float*)d_in[7];
    const float* bhh2  = (const float*)d_in[8];
    const float* fc1_w = (const float*)d_in[9];
    const float* fc1_b = (const float*)d_in[10];
    const float* fc2_w = (const float*)d_in[11];
    const float* fc2_b = (const float*)d_in[12];
    float* out = (float*)d_out;

    const int n_batch = 2048;
    dim3 grid(n_batch / MB), block(BLK);
    lstm_mfma<<<grid, block, 0, stream>>>(x, Wih1, Whh1, bih1, bhh1,
                                          Wih2, Whh2, bih2, bhh2,
                                          fc1_w, fc1_b, fc2_w, fc2_b, out);
}